// Round 7
// baseline (118.457 us; speedup 1.0000x reference)
//
#include <hip/hip_runtime.h>
#include <math.h>

// Output layout: [N][X=32][Y=32][Z=32][3] float32, N=1024.
// val[n,x,y,z,d] = -0.5*t^2 - 0.5*log(2*pi),
//   t = idx_d*s - b_d,  s = pitch*inv,  b_d = (15.5*pitch + p[n,d])*inv,
//   inv = 1/(conf[n]*pitch)   (ALPHA = 1)
//
// R6 experiment: exact structural mimic of fillBufferAligned (6.9-7.0 TB/s):
// small persistent grid (512 blocks = 2/CU), grid-stride comb over float4
// index — the whole grid's in-flight stores form ONE compact ~2MB window
// advancing strictly sequentially (vs R0's ~24MB window / R3's 1024 streams
// / R5's full scatter, all ~5.1 TB/s). Tests DRAM row-locality theory.
// 131072 threads * 16B stride; 25165824 f4 total = exactly 192 iterations.

#define HALF_LOG_2PI 0.91893853320467274178f

typedef float f32x4 __attribute__((ext_vector_type(4)));

__global__ __launch_bounds__(256) void pbt_kernel(
    const float* __restrict__ points,
    const float* __restrict__ confs,
    const float* __restrict__ pitch_p,
    float* __restrict__ out)
{
    const unsigned T = gridDim.x * 256u;                 // 131072 threads
    unsigned f = blockIdx.x * 256u + threadIdx.x;        // global float4 index
    const float pitch = pitch_p[0];
    const float off   = 15.5f * pitch;
    f32x4* o = (f32x4*)out;

    #pragma unroll 2
    for (; f < 25165824u; f += T) {
        // n = f / 24576 (f4 per point = 98304/4); r = remainder
        const unsigned n = f / 24576u;
        const unsigned r = f - n * 24576u;

        const float conf = confs[n];
        const float inv  = 1.0f / (conf * pitch);
        const float s    = pitch * inv;
        const float bx = (off + points[n * 3u + 0u]) * inv;
        const float by = (off + points[n * 3u + 1u]) * inv;
        const float bz = (off + points[n * 3u + 2u]) * inv;

        const unsigned e0 = r * 4u;          // element index within n, < 98304
        float v[4];
        #pragma unroll
        for (int j = 0; j < 4; ++j) {
            const unsigned e  = e0 + (unsigned)j;
            const unsigned zi = e / 3u;      // flat voxel index, < 32768
            const unsigned d  = e - zi * 3u; // axis
            const unsigned xx = zi >> 10;
            const unsigned yy = (zi >> 5) & 31u;
            const unsigned zz = zi & 31u;
            const unsigned ci = (d == 0u) ? xx : ((d == 1u) ? yy : zz);
            const float    b  = (d == 0u) ? bx : ((d == 1u) ? by : bz);
            const float tc = (float)ci * s - b;
            v[j] = fmaf(-0.5f * tc, tc, -HALF_LOG_2PI);
        }
        f32x4 vv = { v[0], v[1], v[2], v[3] };
        o[f] = vv;
    }
}

extern "C" void kernel_launch(void* const* d_in, const int* in_sizes, int n_in,
                              void* d_out, int out_size, void* d_ws, size_t ws_size,
                              hipStream_t stream) {
    const float* points = (const float*)d_in[0];  // [N,3]
    const float* confs  = (const float*)d_in[1];  // [N]
    // d_in[2] = coordinates [32,32,32,3] — recomputed from pitch on device
    const float* pitch  = (const float*)d_in[3];  // [1]
    float* out = (float*)d_out;

    (void)in_sizes; (void)n_in; (void)out_size; (void)d_ws; (void)ws_size;
    pbt_kernel<<<dim3(512), dim3(256), 0, stream>>>(points, confs, pitch, out);
}